// Round 1
// baseline (234.935 us; speedup 1.0000x reference)
//
#include <hip/hip_runtime.h>
#include <math.h>

// Problem constants
#define NB 392      // n = b*oh*ow = 2*14*14
#define NI 288      // K*K*B = 9*32
#define NC 32       // C
#define NQ 16       // PSIZE
#define CQ 512      // NC*NQ
#define CH 544      // B*(PSIZE+1)
#define EPSV 1e-6f

// ws layout (floats)
#define SZ_PIN   (NB*NI*16)            // 1,806,336
#define SZ_AFAC  (NB*NI)               // 112,896
// votes: NB*NI*CQ = 57,802,752 floats (231 MB)

// out layout (floats)
#define OFF_AOUT 200704                 // NB*CQ
#define OFF_CAT  213248                 // OFF_AOUT + NB*NC

// ---------------------------------------------------------------------------
// Gather p_in[n][i][s] from x via the unfold channel-major reinterpret.
// j = p*544 + r*16 + s ; c_idx = j/9 ; ki = (j%9)/3 ; kj = j%3 ; i = p*32+r
__global__ __launch_bounds__(256) void gather_p(const float* __restrict__ x,
                                                float* __restrict__ p_in) {
    int tid = blockIdx.x * 256 + threadIdx.x;
    if (tid >= NB * NI * 16) return;
    int s = tid & 15;
    int i = (tid >> 4) % NI;
    int n = tid / (NI * 16);
    int p = i >> 5;
    int r = i & 31;
    int j = p * CH + r * 16 + s;
    int c_idx = j / 9;
    int rem = j - c_idx * 9;
    int ki = rem / 3;
    int kj = rem - ki * 3;
    int b_ = n / 196;
    int rest = n - b_ * 196;
    int yy = rest / 14;
    int xx = rest - yy * 14;
    int iy = yy + ki - 1;
    int ix = xx + kj - 1;
    float v = 0.f;
    if ((unsigned)iy < 14u && (unsigned)ix < 14u)
        v = x[((b_ * 14 + iy) * 14 + ix) * CH + c_idx];
    p_in[tid] = v;
}

// afac[n][i] = a/(a+eps), a = clip(x_gathered, 1e-4, 1)
__global__ __launch_bounds__(256) void gather_a(const float* __restrict__ x,
                                                float* __restrict__ afac) {
    int tid = blockIdx.x * 256 + threadIdx.x;
    if (tid >= NB * NI) return;
    int i = tid % NI;
    int n = tid / NI;
    int p = i >> 5;
    int r = i & 31;
    int j = p * CH + 512 + r;
    int c_idx = j / 9;
    int rem = j - c_idx * 9;
    int ki = rem / 3;
    int kj = rem - ki * 3;
    int b_ = n / 196;
    int rest = n - b_ * 196;
    int yy = rest / 14;
    int xx = rest - yy * 14;
    int iy = yy + ki - 1;
    int ix = xx + kj - 1;
    float v = 0.f;
    if ((unsigned)iy < 14u && (unsigned)ix < 14u)
        v = x[((b_ * 14 + iy) * 14 + ix) * CH + c_idx];
    float a = fminf(fmaxf(v, 1e-4f), 1.0f);
    afac[tid] = a / (a + EPSV);
}

// ---------------------------------------------------------------------------
// votes[n][i][cq] = sum_p p_in[n][i][p] * W[i][c][p][q]
// Block = (i, half-of-n). W[i] staged in LDS transposed to [p][cq] (bank-safe:
// 2-way aliasing only, which is free on CDNA4).
__global__ __launch_bounds__(256) void votes_k(const float* __restrict__ p_in,
                                               const float* __restrict__ wts,
                                               float* __restrict__ votes) {
    __shared__ float wl[16 * 512];   // 32 KB, [p][cq]
    __shared__ float pl[196 * 16];   // 12.25 KB
    int i = blockIdx.x;
    int half = blockIdx.y;
    int t = threadIdx.x;
    for (int f = t; f < 8192; f += 256) {
        int c = f >> 8;
        int pp = (f >> 4) & 15;
        int qq = f & 15;
        wl[pp * 512 + c * 16 + qq] = wts[i * 8192 + f];
    }
    int n0 = half * 196;
    for (int idx = t; idx < 196 * 16; idx += 256) {
        int nn = idx >> 4;
        int s = idx & 15;
        pl[idx] = p_in[((size_t)(n0 + nn) * NI + i) * 16 + s];
    }
    __syncthreads();
    int cq0 = t, cq1 = t + 256;
    for (int nn = 0; nn < 196; ++nn) {
        float v0 = 0.f, v1 = 0.f;
#pragma unroll
        for (int pp = 0; pp < 16; ++pp) {
            float a = pl[nn * 16 + pp];
            v0 += a * wl[pp * 512 + cq0];
            v1 += a * wl[pp * 512 + cq1];
        }
        size_t base = ((size_t)(n0 + nn) * NI + i) * CQ;
        votes[base + cq0] = v0;
        votes[base + cq1] = v1;
    }
}

// ---------------------------------------------------------------------------
// Fused dynamic routing: one block per n, 4 waves; each wave owns i-range.
// Lane l: c = l>>1, q-half = (l&1)*8. s_j accumulated in registers, reduced
// across waves via LDS. Softmax over C via 64-lane shfl (each c duplicated x2).
__global__ __launch_bounds__(256) void routing_k(const float* __restrict__ votes,
                                                 const float* __restrict__ afac,
                                                 float* __restrict__ out) {
    __shared__ float bij[NI * NC];   // 36 KB
    __shared__ float afs[NI];
    __shared__ float sred[4 * CQ];   // 8 KB
    __shared__ float vj[CQ];
    __shared__ float aout_s[NC];

    int n = blockIdx.x;
    int t = threadIdx.x;
    int wv = t >> 6;
    int l = t & 63;
    int c = l >> 1;

    for (int idx = t; idx < NI; idx += 256) afs[idx] = afac[n * NI + idx];
    for (int idx = t; idx < NI * NC; idx += 256) bij[idx] = 0.f;
    __syncthreads();

    const float* vbase = votes + (size_t)n * NI * CQ;
    float vjr[8];
    float sreg[8];

    for (int iter = 0; iter < 3; ++iter) {
#pragma unroll
        for (int j = 0; j < 8; ++j) sreg[j] = 0.f;

        // prefetch first i
        const float4* vp0 = (const float4*)(vbase + (size_t)(wv * 72) * CQ + l * 8);
        float4 va = vp0[0], vb = vp0[1];

        for (int k = 0; k < 72; ++k) {
            int i = wv * 72 + k;
            float4 vc = va, vd = vb;
            if (k < 71) {
                const float4* vpn = (const float4*)(vbase + (size_t)(i + 1) * CQ + l * 8);
                vc = vpn[0];
                vd = vpn[1];
            }
            float vt[8] = {va.x, va.y, va.z, va.w, vb.x, vb.y, vb.z, vb.w};
            float cij;
            if (iter == 0) {
                cij = afs[i] * (1.0f / 32.0f);
            } else {
                float ah = 0.f;
#pragma unroll
                for (int j = 0; j < 8; ++j) ah += vt[j] * vjr[j];
                float agr = ah + __shfl_xor(ah, 1);
                float bnew = bij[i * NC + c] + agr;
                if ((l & 1) == 0) bij[i * NC + c] = bnew;
                float m = bnew;
#pragma unroll
                for (int off = 1; off < 64; off <<= 1) m = fmaxf(m, __shfl_xor(m, off));
                float e = __expf(bnew - m);
                float ssum = e;
#pragma unroll
                for (int off = 1; off < 64; off <<= 1) ssum += __shfl_xor(ssum, off);
                cij = (2.0f * e / ssum) * afs[i];   // softmax = e / (ssum/2)
            }
#pragma unroll
            for (int j = 0; j < 8; ++j) sreg[j] += cij * vt[j];
            va = vc;
            vb = vd;
        }

        // cross-wave s_j reduction
#pragma unroll
        for (int j = 0; j < 8; ++j) sred[wv * CQ + l * 8 + j] = sreg[j];
        __syncthreads();
        for (int idx = t; idx < CQ; idx += 256) {
            float s = sred[idx] + sred[CQ + idx] + sred[2 * CQ + idx] + sred[3 * CQ + idx];
            sred[idx] = s;   // per-thread idx: no overlap with other readers
        }
        __syncthreads();

        // squash (threads 0..31, one c each)
        if (t < NC) {
            float s2 = 0.f;
#pragma unroll
            for (int q = 0; q < 16; ++q) {
                float s = sred[t * 16 + q];
                s2 += s * s;
            }
            float f = (s2 / (1.f + s2)) / sqrtf(s2 + EPSV);
            float vn2 = 0.f;
#pragma unroll
            for (int q = 0; q < 16; ++q) {
                float v = f * sred[t * 16 + q];
                vj[t * 16 + q] = v;
                vn2 += v * v;
            }
            if (iter == 2) {
                float ao = sqrtf(vn2 + EPSV);
                ao = fminf(fmaxf(ao, 1e-4f), 1.f - 1e-4f);
                aout_s[t] = ao;
            }
        }
        __syncthreads();
        if (iter < 2) {
#pragma unroll
            for (int j = 0; j < 8; ++j) vjr[j] = vj[l * 8 + j];
        }
    }

    // outputs: p_out, a_out, concat(out)
    for (int idx = t; idx < CQ; idx += 256) {
        float v = vj[idx];
        out[(size_t)n * CQ + idx] = v;
        out[OFF_CAT + (size_t)n * 544 + idx] = v;
    }
    if (t < NC) {
        float ao = aout_s[t];
        out[OFF_AOUT + n * 32 + t] = ao;
        out[OFF_CAT + (size_t)n * 544 + 512 + t] = ao;
    }
}

// ---------------------------------------------------------------------------
extern "C" void kernel_launch(void* const* d_in, const int* in_sizes, int n_in,
                              void* d_out, int out_size, void* d_ws, size_t ws_size,
                              hipStream_t stream) {
    const float* x = (const float*)d_in[0];
    const float* wts = (const float*)d_in[1];
    float* out = (float*)d_out;
    float* ws = (float*)d_ws;

    float* p_in = ws;
    float* afac = ws + SZ_PIN;
    float* votes = ws + SZ_PIN + SZ_AFAC;

    hipLaunchKernelGGL(gather_p, dim3((NB * NI * 16 + 255) / 256), dim3(256), 0, stream,
                       x, p_in);
    hipLaunchKernelGGL(gather_a, dim3((NB * NI + 255) / 256), dim3(256), 0, stream,
                       x, afac);
    hipLaunchKernelGGL(votes_k, dim3(NI, 2), dim3(256), 0, stream,
                       p_in, wts, votes);
    hipLaunchKernelGGL(routing_k, dim3(NB), dim3(256), 0, stream,
                       votes, afac, out);
}

// Round 2
// 177.728 us; speedup vs baseline: 1.3219x; 1.3219x over previous
//
#include <hip/hip_runtime.h>
#include <hip/hip_fp16.h>
#include <math.h>

// Problem constants
#define NB 392      // n = b*oh*ow = 2*14*14
#define NI 288      // K*K*B = 9*32
#define NC 32       // C
#define NQ 16       // PSIZE
#define CQ 512      // NC*NQ
#define CH 544      // B*(PSIZE+1)
#define EPSV 1e-6f

// ws layout
#define SZ_PIN   (NB*NI*16)            // floats
#define SZ_AFAC  (NB*NI)               // floats
// votes: NB*NI*CQ fp16 after the float region (byte offset 16B-aligned)

// out layout (floats)
#define OFF_AOUT 200704                 // NB*CQ
#define OFF_CAT  213248                 // OFF_AOUT + NB*NC

// ---------------------------------------------------------------------------
// Fused gather: p_in[n][i][s] and afac[n][i] from x via the unfold
// channel-major reinterpret. j = p*544 + (inner) ; c_idx=j/9 ; ki=(j%9)/3 ; kj=j%3
__global__ __launch_bounds__(256) void gather_k(const float* __restrict__ x,
                                                float* __restrict__ p_in,
                                                float* __restrict__ afac) {
    int tid = blockIdx.x * 256 + threadIdx.x;
    if (tid < NB * NI * 16) {
        int s = tid & 15;
        int i = (tid >> 4) % NI;
        int n = tid / (NI * 16);
        int p = i >> 5;
        int r = i & 31;
        int j = p * CH + r * 16 + s;
        int c_idx = j / 9;
        int rem = j - c_idx * 9;
        int ki = rem / 3;
        int kj = rem - ki * 3;
        int b_ = n / 196;
        int rest = n - b_ * 196;
        int yy = rest / 14;
        int xx = rest - yy * 14;
        int iy = yy + ki - 1;
        int ix = xx + kj - 1;
        float v = 0.f;
        if ((unsigned)iy < 14u && (unsigned)ix < 14u)
            v = x[((b_ * 14 + iy) * 14 + ix) * CH + c_idx];
        p_in[tid] = v;
    } else if (tid < NB * NI * 16 + NB * NI) {
        int t2 = tid - NB * NI * 16;
        int i = t2 % NI;
        int n = t2 / NI;
        int p = i >> 5;
        int r = i & 31;
        int j = p * CH + 512 + r;
        int c_idx = j / 9;
        int rem = j - c_idx * 9;
        int ki = rem / 3;
        int kj = rem - ki * 3;
        int b_ = n / 196;
        int rest = n - b_ * 196;
        int yy = rest / 14;
        int xx = rest - yy * 14;
        int iy = yy + ki - 1;
        int ix = xx + kj - 1;
        float v = 0.f;
        if ((unsigned)iy < 14u && (unsigned)ix < 14u)
            v = x[((b_ * 14 + iy) * 14 + ix) * CH + c_idx];
        float a = fminf(fmaxf(v, 1e-4f), 1.0f);
        afac[t2] = a / (a + EPSV);
    }
}

// ---------------------------------------------------------------------------
// votes[n][i][cq] = sum_p p_in[n][i][p] * W[i][c][p][q], stored fp16.
// Block = (i, half-of-n). W[i] staged in LDS transposed to [p][cq].
__global__ __launch_bounds__(256) void votes_k(const float* __restrict__ p_in,
                                               const float* __restrict__ wts,
                                               ushort* __restrict__ votes) {
    __shared__ float wl[16 * 512];   // 32 KB, [p][cq]
    __shared__ float pl[196 * 16];   // 12.25 KB
    int i = blockIdx.x;
    int half = blockIdx.y;
    int t = threadIdx.x;
    for (int f = t; f < 8192; f += 256) {
        int c = f >> 8;
        int pp = (f >> 4) & 15;
        int qq = f & 15;
        wl[pp * 512 + c * 16 + qq] = wts[i * 8192 + f];
    }
    int n0 = half * 196;
    for (int idx = t; idx < 196 * 16; idx += 256) {
        int nn = idx >> 4;
        int s = idx & 15;
        pl[idx] = p_in[((size_t)(n0 + nn) * NI + i) * 16 + s];
    }
    __syncthreads();
    const float2* wl2 = (const float2*)wl;
    for (int nn = 0; nn < 196; ++nn) {
        float v0 = 0.f, v1 = 0.f;
#pragma unroll
        for (int pp = 0; pp < 16; ++pp) {
            float a = pl[nn * 16 + pp];
            float2 w = wl2[pp * 256 + t];
            v0 += a * w.x;
            v1 += a * w.y;
        }
        __half2 h = __floats2half2_rn(v0, v1);
        uint* row = (uint*)(votes + ((size_t)(n0 + nn) * NI + i) * CQ);
        row[t] = *(uint*)&h;
    }
}

// ---------------------------------------------------------------------------
// Fused dynamic routing: one block per n, 8 waves; wave wv owns i in
// [wv*36, wv*36+36). Lane l: c=l>>1, q-half=(l&1)*8. Votes are fp16: one
// dwordx4 (8 halves) per lane per i, depth-2 prefetch.
__global__ __launch_bounds__(512) void routing_k(const ushort* __restrict__ votes,
                                                 const float* __restrict__ afac,
                                                 float* __restrict__ out) {
    __shared__ float bij[NI * NC];   // 36 KB
    __shared__ float afs[NI];
    __shared__ float sred[8 * CQ];   // 16 KB
    __shared__ float vj[CQ];
    __shared__ float aout_s[NC];

    int n = blockIdx.x;
    int t = threadIdx.x;
    int wv = t >> 6;
    int l = t & 63;
    int c = l >> 1;

    for (int idx = t; idx < NI; idx += 512) afs[idx] = afac[n * NI + idx];
    for (int idx = t; idx < NI * NC; idx += 512) bij[idx] = 0.f;
    __syncthreads();

    const ushort* vbase = votes + (size_t)n * NI * CQ;
    float vjr[8];
    float sreg[8];
    const int i0 = wv * 36;

    for (int iter = 0; iter < 3; ++iter) {
#pragma unroll
        for (int j = 0; j < 8; ++j) sreg[j] = 0.f;

        // depth-2 prefetch pipeline
        uint4 buf0 = ((const uint4*)(vbase + (size_t)i0 * CQ))[l];
        uint4 buf1 = ((const uint4*)(vbase + (size_t)(i0 + 1) * CQ))[l];

        for (int k = 0; k < 36; ++k) {
            int i = i0 + k;
            uint4 cur = buf0;
            buf0 = buf1;
            if (k + 2 < 36)
                buf1 = ((const uint4*)(vbase + (size_t)(i + 2) * CQ))[l];

            float vt[8];
            {
                float2 f;
                f = __half22float2(*(const __half2*)&cur.x); vt[0] = f.x; vt[1] = f.y;
                f = __half22float2(*(const __half2*)&cur.y); vt[2] = f.x; vt[3] = f.y;
                f = __half22float2(*(const __half2*)&cur.z); vt[4] = f.x; vt[5] = f.y;
                f = __half22float2(*(const __half2*)&cur.w); vt[6] = f.x; vt[7] = f.y;
            }

            float cij;
            if (iter == 0) {
                cij = afs[i] * (1.0f / 32.0f);
            } else {
                float ah = 0.f;
#pragma unroll
                for (int j = 0; j < 8; ++j) ah += vt[j] * vjr[j];
                float agr = ah + __shfl_xor(ah, 1);
                float bnew = bij[i * NC + c] + agr;
                if ((l & 1) == 0) bij[i * NC + c] = bnew;
                float m = bnew;
#pragma unroll
                for (int off = 1; off < 64; off <<= 1) m = fmaxf(m, __shfl_xor(m, off));
                float e = __expf(bnew - m);
                float ssum = e;
#pragma unroll
                for (int off = 1; off < 64; off <<= 1) ssum += __shfl_xor(ssum, off);
                cij = (2.0f * e / ssum) * afs[i];   // softmax = e / (ssum/2)
            }
#pragma unroll
            for (int j = 0; j < 8; ++j) sreg[j] += cij * vt[j];
        }

        // cross-wave s_j reduction
#pragma unroll
        for (int j = 0; j < 8; ++j) sred[wv * CQ + l * 8 + j] = sreg[j];
        __syncthreads();
        {
            int idx = t;  // 512 threads == CQ
            float s = 0.f;
#pragma unroll
            for (int w = 0; w < 8; ++w) s += sred[w * CQ + idx];
            sred[idx] = s;
        }
        __syncthreads();

        // squash (threads 0..31, one c each)
        if (t < NC) {
            float s2 = 0.f;
#pragma unroll
            for (int q = 0; q < 16; ++q) {
                float s = sred[t * 16 + q];
                s2 += s * s;
            }
            float f = (s2 / (1.f + s2)) / sqrtf(s2 + EPSV);
            float vn2 = 0.f;
#pragma unroll
            for (int q = 0; q < 16; ++q) {
                float v = f * sred[t * 16 + q];
                vj[t * 16 + q] = v;
                vn2 += v * v;
            }
            if (iter == 2) {
                float ao = sqrtf(vn2 + EPSV);
                ao = fminf(fmaxf(ao, 1e-4f), 1.f - 1e-4f);
                aout_s[t] = ao;
            }
        }
        __syncthreads();
        if (iter < 2) {
#pragma unroll
            for (int j = 0; j < 8; ++j) vjr[j] = vj[l * 8 + j];
        }
    }

    // outputs: p_out, a_out, concat(out)
    {
        int idx = t;  // 512 threads == CQ
        float v = vj[idx];
        out[(size_t)n * CQ + idx] = v;
        out[OFF_CAT + (size_t)n * 544 + idx] = v;
    }
    if (t < NC) {
        float ao = aout_s[t];
        out[OFF_AOUT + n * 32 + t] = ao;
        out[OFF_CAT + (size_t)n * 544 + 512 + t] = ao;
    }
}

// ---------------------------------------------------------------------------
extern "C" void kernel_launch(void* const* d_in, const int* in_sizes, int n_in,
                              void* d_out, int out_size, void* d_ws, size_t ws_size,
                              hipStream_t stream) {
    const float* x = (const float*)d_in[0];
    const float* wts = (const float*)d_in[1];
    float* out = (float*)d_out;
    float* ws = (float*)d_ws;

    float* p_in = ws;
    float* afac = ws + SZ_PIN;
    ushort* votes = (ushort*)(ws + SZ_PIN + SZ_AFAC);

    hipLaunchKernelGGL(gather_k, dim3((NB * NI * 17 + 255) / 256), dim3(256), 0, stream,
                       x, p_in, afac);
    hipLaunchKernelGGL(votes_k, dim3(NI, 2), dim3(256), 0, stream,
                       p_in, wts, votes);
    hipLaunchKernelGGL(routing_k, dim3(NB), dim3(512), 0, stream,
                       votes, afac, out);
}